// Round 4
// baseline (266.810 us; speedup 1.0000x reference)
//
#include <hip/hip_runtime.h>
#include <math.h>
#include <stdint.h>

#define NTOT   8192
#define HALF_N 4096
#define DIM    512
#define INV_T  14.2857142857142857f   // 1/0.07
#define NTILE  64                     // 8192 / 128
#define NBLK   2080                   // 64*65/2 triangular; 2080 % 8 == 0

using s16x8 = __attribute__((ext_vector_type(8))) short;
using f32x4 = __attribute__((ext_vector_type(4))) float;

// Scratch in static device globals (fully rewritten every call; no d_ws use).
__device__ unsigned short g_fnb[NTOT * DIM];   // normalized bf16 matrix, 8 MB
__device__ float g_pos[NTOT];
__device__ float g_ps[(size_t)NTILE * NTOT];   // per-slot sumexp partials, 2 MB
__device__ int   g_pc[(size_t)NTILE * NTOT];   // per-slot count partials, 2 MB
__device__ float g_part[NTILE * 4];            // per-slab scalar partials
__device__ int   g_tick[NTILE];                // per-slab writer arrival tickets
__device__ int   g_tick2;                      // slab-fold arrival ticket

// super-tile decode tables: 4x4 upper-triangle of 16x16 slab groups.
// sizes: diag super = 136 (16*17/2), full super = 256.
__constant__ int c_pre[11] = {0,136,392,648,904,1040,1296,1552,1688,1944,2080};
__constant__ int c_gi[10]  = {0,0,0,0,1,1,1,2,2,3};
__constant__ int c_gj[10]  = {0,1,2,3,1,2,3,2,3,3};

__device__ __forceinline__ float bf2f(unsigned short u) {
  union { unsigned int i; float f; } v; v.i = ((unsigned int)u) << 16; return v.f;
}
__device__ __forceinline__ unsigned short f2bf(float x) {
  union { float f; unsigned int i; } v; v.f = x;
  unsigned int u = v.i;
  return (unsigned short)((u + 0x7FFFu + ((u >> 16) & 1u)) >> 16);
}

// async global->LDS, 16 B per lane. LDS dest is wave-uniform base + lane*16.
__device__ __forceinline__ void gload16(const unsigned short* g, unsigned short* l) {
  __builtin_amdgcn_global_load_lds(
      (const __attribute__((address_space(1))) unsigned int*)g,
      (__attribute__((address_space(3))) unsigned int*)l, 16, 0, 0);
}

// ---------------- kernel 1: normalize pairs -> bf16, pos, zero tickets ----------------
__global__ __launch_bounds__(256) void knorm(const float* __restrict__ f1,
                                             const float* __restrict__ f2) {
  const int tid  = threadIdx.x;
  const int wv   = tid >> 6;
  const int pi   = wv >> 1;            // pair within block
  const int half = wv & 1;             // 0: f1 row, 1: f2 row
  const int lane = tid & 63;
  const int b    = blockIdx.x * 2 + pi;
  const int row  = b + half * HALF_N;

  if (blockIdx.x == 0) {               // reset tickets for this iteration
    if (tid < NTILE)
      __hip_atomic_store(&g_tick[tid], 0, __ATOMIC_RELAXED, __HIP_MEMORY_SCOPE_AGENT);
    else if (tid == NTILE)
      __hip_atomic_store(&g_tick2, 0, __ATOMIC_RELAXED, __HIP_MEMORY_SCOPE_AGENT);
  }

  const float* src = (half == 0) ? (f1 + (size_t)b * DIM) : (f2 + (size_t)b * DIM);
  float4 v0 = ((const float4*)src)[lane];
  float4 v1 = ((const float4*)src)[lane + 64];
  float ss = v0.x*v0.x + v0.y*v0.y + v0.z*v0.z + v0.w*v0.w
           + v1.x*v1.x + v1.y*v1.y + v1.z*v1.z + v1.w*v1.w;
  #pragma unroll
  for (int o = 32; o >= 1; o >>= 1) ss += __shfl_xor(ss, o, 64);
  const float sc = 1.0f / fmaxf(sqrtf(ss), 1e-8f);
  ushort4 h0, h1;
  h0.x = f2bf(v0.x * sc); h0.y = f2bf(v0.y * sc);
  h0.z = f2bf(v0.z * sc); h0.w = f2bf(v0.w * sc);
  h1.x = f2bf(v1.x * sc); h1.y = f2bf(v1.y * sc);
  h1.z = f2bf(v1.z * sc); h1.w = f2bf(v1.w * sc);
  ushort4* dst = (ushort4*)(g_fnb + (size_t)row * DIM);
  dst[lane]      = h0;
  dst[lane + 64] = h1;

  // pos[b] = <fn_b, fn_{b+4096}> on the same bf16 values the GEMM uses
  __shared__ ushort4 sh[2][64][2];
  if (half == 1) { sh[pi][lane][0] = h0; sh[pi][lane][1] = h1; }
  __syncthreads();
  if (half == 0) {
    const ushort4 p0 = sh[pi][lane][0], p1 = sh[pi][lane][1];
    float s = bf2f(h0.x)*bf2f(p0.x) + bf2f(h0.y)*bf2f(p0.y)
            + bf2f(h0.z)*bf2f(p0.z) + bf2f(h0.w)*bf2f(p0.w)
            + bf2f(h1.x)*bf2f(p1.x) + bf2f(h1.y)*bf2f(p1.y)
            + bf2f(h1.z)*bf2f(p1.z) + bf2f(h1.w)*bf2f(p1.w);
    #pragma unroll
    for (int o = 32; o >= 1; o >>= 1) s += __shfl_xor(s, o, 64);
    if (lane == 0) { g_pos[b] = s; g_pos[b + HALF_N] = s; }
  }
}

// ---------------- kernel 2: GEMM + slot stores + ticketed fold + finalize ----------------
// R4: (a) super-tile schedule: 16x16-slab supers keep each XCD's instantaneous
// working set at 16 A + 16 B slabs = 4 MB = one L2 (R3's bi-runs swept ~8 MB of
// B slabs -> 112 MB LLC fetch at ~2 TB/s was the wall). (b) kred+kfin fused in
// via per-slab tickets: after slot stores + __syncthreads, tid0 does an
// ACQ_REL/AGENT fetch_add on g_tick[slab]; the 64th arrival folds the slab
// (fixed slot order -> deterministic), writes g_part[slab], and the 64th
// arrival on g_tick2 sums g_part in fixed order -> out. No spins; cross-XCD
// visibility from the RMW's wbl2/inv sequence + explicit agent acquire fences.
__global__ __launch_bounds__(256, 4) void kmain(float* __restrict__ out) {
  __shared__ __align__(16) unsigned short As[128 * 64];
  __shared__ __align__(16) unsigned short Bs[128 * 64];
  __shared__ float sRowS[128]; __shared__ int sRowC[128];
  __shared__ float sColS[128]; __shared__ int sColC[128];
  __shared__ int sFold;

  // XCD swizzle: contiguous t-range of 260 per XCD (~ one super-tile each)
  const int t_sw = (blockIdx.x & 7) * (NBLK / 8) + (blockIdx.x >> 3);
  // super-tile decode: t -> super sp -> (bi, bj), bi <= bj
  int sp = 0;
  while (t_sw >= c_pre[sp + 1]) ++sp;
  int l = t_sw - c_pre[sp];
  int lbi, lbj;
  if (c_gi[sp] == c_gj[sp]) {          // diagonal super: triangular 16
    int r16 = 16; lbi = 0;
    while (l >= r16) { l -= r16; --r16; ++lbi; }
    lbj = lbi + l;
  } else {                             // full super: row-major (A-slab runs)
    lbi = l >> 4; lbj = l & 15;
  }
  const int bi = c_gi[sp] * 16 + lbi;
  const int bj = c_gj[sp] * 16 + lbj;
  const bool offdiag = (bi != bj);
  const int i0 = bi * 128, j0 = bj * 128;

  const int tid  = threadIdx.x;
  const int lane = tid & 63;
  const int w    = tid >> 6;
  const int wr   = (w >> 1) * 64;   // wave row base
  const int wc   = (w & 1) * 64;    // wave col base
  const int lrow = lane & 15;
  const int lq   = lane >> 4;

  // staging: wave w covers tile rows [w*32, w*32+32) in 4 chunks of 8 rows.
  // Linear LDS dest; inverse-XOR-swizzled global source (rule #21).
  const int rsub = lane >> 3;
  const int lcb  = (lane & 7) ^ rsub;
  const unsigned short* Ag = g_fnb + (size_t)(i0 + w * 32 + rsub) * DIM + lcb * 8;
  const unsigned short* Bg = g_fnb + (size_t)(j0 + w * 32 + rsub) * DIM + lcb * 8;
  unsigned short* Al = &As[w * 32 * 64];
  unsigned short* Bl = &Bs[w * 32 * 64];

  f32x4 acc[4][4];
  #pragma unroll
  for (int a = 0; a < 4; ++a)
    #pragma unroll
    for (int bb = 0; bb < 4; ++bb) { acc[a][bb][0]=0.f; acc[a][bb][1]=0.f; acc[a][bb][2]=0.f; acc[a][bb][3]=0.f; }

  const unsigned short* Bls = offdiag ? (const unsigned short*)Bs
                                      : (const unsigned short*)As;

  for (int kt = 0; kt < 8; ++kt) {
    __syncthreads();                       // prev compute done, LDS reusable
    const int kb = kt * 64;
    #pragma unroll
    for (int q = 0; q < 4; ++q) {
      gload16(Ag + (size_t)(q * 8) * DIM + kb, Al + q * 512);
      if (offdiag) gload16(Bg + (size_t)(q * 8) * DIM + kb, Bl + q * 512);
    }
    __syncthreads();                       // vmcnt(0) drains here -> tile kt visible

    #pragma unroll
    for (int kk = 0; kk < 2; ++kk) {
      s16x8 af[4], bf[4];
      #pragma unroll
      for (int mi = 0; mi < 4; ++mi) {
        const int r = wr + mi * 16 + lrow;
        af[mi] = *(const s16x8*)(&As[r * 64 + (((kk * 4 + lq) ^ (lrow & 7)) * 8)]);
      }
      #pragma unroll
      for (int ni = 0; ni < 4; ++ni) {
        const int r = wc + ni * 16 + lrow;
        bf[ni] = *(const s16x8*)(&Bls[r * 64 + (((kk * 4 + lq) ^ (lrow & 7)) * 8)]);
      }
      #pragma unroll
      for (int mi = 0; mi < 4; ++mi)
        #pragma unroll
        for (int ni = 0; ni < 4; ++ni)
          acc[mi][ni] = __builtin_amdgcn_mfma_f32_16x16x32_bf16(af[mi], bf[ni], acc[mi][ni], 0, 0, 0);
    }
  }

  // ---- epilogue: LDS-combine partials, plain slot stores (no global atomics) ----
  if (tid < 128) { sRowS[tid] = 0.f; sRowC[tid] = 0; sColS[tid] = 0.f; sColC[tid] = 0; }
  __syncthreads();

  // row side (always): 2 waves contribute per row (wc=0 / wc=64)
  #pragma unroll
  for (int mi = 0; mi < 4; ++mi) {
    #pragma unroll
    for (int r = 0; r < 4; ++r) {
      const int ridx = wr + mi * 16 + lq * 4 + r;     // 0..127
      const int i  = i0 + ridx;
      const float pv = g_pos[i];
      float s = 0.f; int c = 0;
      #pragma unroll
      for (int ni = 0; ni < 4; ++ni) {
        const int j = j0 + wc + ni * 16 + lrow;
        const float v = acc[mi][ni][r];
        const float e = __expf(v * INV_T);
        const bool diag = (j == i);
        s += diag ? 0.f : e;
        c += (!diag && (j != (i ^ HALF_N)) && (v > pv)) ? 1 : 0;
      }
      #pragma unroll
      for (int o = 1; o < 16; o <<= 1) {
        s += __shfl_xor(s, o, 64);
        c += __shfl_xor(c, o, 64);
      }
      if (lrow == 0) {
        atomicAdd(&sRowS[ridx], s);
        atomicAdd(&sRowC[ridx], c);
      }
    }
  }

  // col side (off-diagonal only): 2 waves contribute per col (wr=0 / wr=64)
  if (offdiag) {
    #pragma unroll
    for (int ni = 0; ni < 4; ++ni) {
      const int cidx = wc + ni * 16 + lrow;           // 0..127
      const int j  = j0 + cidx;
      const float pj = g_pos[j];
      float s = 0.f; int c = 0;
      #pragma unroll
      for (int mi = 0; mi < 4; ++mi) {
        #pragma unroll
        for (int r = 0; r < 4; ++r) {
          const int i = i0 + wr + mi * 16 + lq * 4 + r;
          const float v = acc[mi][ni][r];
          s += __expf(v * INV_T);
          c += ((i != (j ^ HALF_N)) && (v > pj)) ? 1 : 0;
        }
      }
      s += __shfl_xor(s, 16, 64); s += __shfl_xor(s, 32, 64);
      c += __shfl_xor(c, 16, 64); c += __shfl_xor(c, 32, 64);
      if (lq == 0) {
        atomicAdd(&sColS[cidx], s);
        atomicAdd(&sColC[cidx], c);
      }
    }
  }
  __syncthreads();

  // slot stores: row side -> slab bi slot bj; col side -> slab bj slot bi
  if (tid < 128) {
    g_ps[(size_t)bj * NTOT + i0 + tid] = sRowS[tid];
    g_pc[(size_t)bj * NTOT + i0 + tid] = sRowC[tid];
  } else if (offdiag && tid < 256) {
    const int r2 = tid - 128;
    g_ps[(size_t)bi * NTOT + j0 + r2] = sColS[r2];
    g_pc[(size_t)bi * NTOT + j0 + r2] = sColC[r2];
  }
  __syncthreads();   // all slot stores issued & drained (barrier waits vmcnt)

  // ---- ticketed fold: 64th writer of a slab folds it; 64th fold finalizes ----
  for (int side = 0; side < 2; ++side) {
    if (tid == 0) {
      int f = -1;
      if (side == 0 || offdiag) {
        const int s = (side == 0) ? bi : bj;
        const int old = __hip_atomic_fetch_add(&g_tick[s], 1,
                            __ATOMIC_ACQ_REL, __HIP_MEMORY_SCOPE_AGENT);
        if (old == NTILE - 1) f = s;
      }
      sFold = f;
    }
    __syncthreads();
    const int s = sFold;
    if (s >= 0) {
      __builtin_amdgcn_fence(__ATOMIC_ACQUIRE, "agent");  // invalidate stale lines
      const int hh = tid >> 7;          // 0: slots 0..31, 1: slots 32..63
      const int rr = tid & 127;
      const int i  = s * 128 + rr;
      float fs = 0.f; int fc = 0;
      const int sl0 = hh * 32;
      #pragma unroll 8
      for (int sl = sl0; sl < sl0 + 32; ++sl) {
        fs += g_ps[(size_t)sl * NTOT + i];
        fc += g_pc[(size_t)sl * NTOT + i];
      }
      if (hh) { sColS[rr] = fs; sColC[rr] = fc; }
      __syncthreads();
      float nll = 0.f, t1 = 0.f, t5 = 0.f, mr = 0.f;
      if (!hh) {
        const float se = fs + sColS[rr];       // fixed order: low + high
        const int   c  = fc + sColC[rr];
        nll = -g_pos[i] * INV_T + logf(se);
        t1 = (c == 0) ? 1.f : 0.f;
        t5 = (c < 5) ? 1.f : 0.f;
        mr = (float)c;
      }
      #pragma unroll
      for (int o = 32; o >= 1; o >>= 1) {
        nll += __shfl_xor(nll, o, 64);
        t1  += __shfl_xor(t1, o, 64);
        t5  += __shfl_xor(t5, o, 64);
        mr  += __shfl_xor(mr, o, 64);
      }
      if (tid == 64) { sColS[0] = nll; sColS[1] = t1; sColS[2] = t5; sColS[3] = mr; }
      __syncthreads();
      if (tid == 0) {
        nll += sColS[0]; t1 += sColS[1]; t5 += sColS[2]; mr += sColS[3];
        g_part[s * 4 + 0] = nll;
        g_part[s * 4 + 1] = t1;
        g_part[s * 4 + 2] = t5;
        g_part[s * 4 + 3] = mr;
        const int o2 = __hip_atomic_fetch_add(&g_tick2, 1,
                           __ATOMIC_ACQ_REL, __HIP_MEMORY_SCOPE_AGENT);
        if (o2 == NTILE - 1) {                 // last fold: finalize, fixed order
          __builtin_amdgcn_fence(__ATOMIC_ACQUIRE, "agent");
          float a = 0.f, b = 0.f, cc = 0.f, d = 0.f;
          for (int k2 = 0; k2 < NTILE; ++k2) {
            a  += g_part[k2 * 4 + 0];
            b  += g_part[k2 * 4 + 1];
            cc += g_part[k2 * 4 + 2];
            d  += g_part[k2 * 4 + 3];
          }
          out[0] = a / (float)NTOT;
          out[1] = b / (float)NTOT;
          out[2] = cc / (float)NTOT;
          out[3] = 1.f + d / (float)NTOT;
        }
      }
    }
    __syncthreads();
  }
}

extern "C" void kernel_launch(void* const* d_in, const int* in_sizes, int n_in,
                              void* d_out, int out_size, void* d_ws, size_t ws_size,
                              hipStream_t stream) {
  const float* f1 = (const float*)d_in[0];
  const float* f2 = (const float*)d_in[1];
  float* out = (float*)d_out;

  knorm<<<dim3(2048), dim3(256), 0, stream>>>(f1, f2);
  kmain<<<dim3(NBLK), dim3(256), 0, stream>>>(out);
}